// Round 1
// baseline (517.601 us; speedup 1.0000x reference)
//
#include <hip/hip_runtime.h>

#define Bn 8
#define Hn 512
#define Wn 512
#define Cn 16

// ---------------- x-channel: cumsum along W per (b,h) row ----------------
__global__ void grid_x_kernel(const float* __restrict__ defgrad,
                              float* __restrict__ grid_norm,
                              float* __restrict__ grid_inv) {
    __shared__ float s[512];
    const int row = blockIdx.x;            // b*H + h
    const int t   = threadIdx.x;           // w
    const long base = (long)row * Wn;      // pixel index of (b,h,0)
    float g = defgrad[(base + t) * 2 + 0];
    float v = 2.0f / (1.0f + expf(-g));    // dg = c/(1+(c-1)exp(-x)), c=2
    s[t] = v;
    __syncthreads();
    // inclusive Hillis-Steele scan
    for (int off = 1; off < 512; off <<= 1) {
        float add = (t >= off) ? s[t - off] : 0.0f;
        __syncthreads();
        s[t] += add;
        __syncthreads();
    }
    float s0    = s[0];            // first element (min_x + 1)
    float denom = s[511] - s0;     // max_x - min_x
    float norm  = 511.0f * ((s[t] - s0) / denom);
    long o = (base + t) * 2;
    grid_norm[o] = norm;
    grid_inv[o]  = 2.0f * (float)t - norm;
}

// ---------------- y-channel: cumsum along H per (b,w) column ----------------
// One block = (b, 64-column tile). 8 waves; wave i owns h in [64i, 64i+64).
__global__ void grid_y_kernel(const float* __restrict__ defgrad,
                              float* __restrict__ grid_norm,
                              float* __restrict__ grid_inv) {
    __shared__ float partial[8][64];
    __shared__ float e0s[64];
    const int b    = blockIdx.x >> 3;
    const int w0   = (blockIdx.x & 7) * 64;
    const int wave = threadIdx.x >> 6;
    const int lane = threadIdx.x & 63;
    const int w    = w0 + lane;
    const long cbase = ((long)b * Hn) * Wn + w;   // pixel index at (b,0,w)

    // pass 1: per-wave partial sums of dg_y over 64 rows
    float sum = 0.f;
    for (int i = 0; i < 64; ++i) {
        int h = wave * 64 + i;
        float g = defgrad[(cbase + (long)h * Wn) * 2 + 1];
        float v = 2.0f / (1.0f + expf(-g));
        if (wave == 0 && i == 0) e0s[lane] = v;
        sum += v;
    }
    partial[wave][lane] = sum;
    __syncthreads();

    float off = 0.f, tot = 0.f;
    for (int j = 0; j < 8; ++j) {
        float p = partial[j][lane];
        if (j < wave) off += p;
        tot += p;
    }
    float e0    = e0s[lane];
    float denom = tot - e0;

    // pass 2: recompute running prefix, write normalized
    float run = off;
    for (int i = 0; i < 64; ++i) {
        int h = wave * 64 + i;
        long pidx = cbase + (long)h * Wn;
        float g = defgrad[pidx * 2 + 1];
        float v = 2.0f / (1.0f + expf(-g));
        run += v;
        float norm = 511.0f * ((run - e0) / denom);
        grid_norm[pidx * 2 + 1] = norm;
        grid_inv[pidx * 2 + 1]  = 2.0f * (float)h - norm;
    }
}

// ---------------- bilinear resample: 4 threads per pixel (float4 per thread) ----------------
__global__ void resample_kernel(const float* __restrict__ im,
                                const float* __restrict__ grid,
                                float* __restrict__ out) {
    long gid = (long)blockIdx.x * blockDim.x + threadIdx.x;
    long pix = gid >> 2;
    int  cg  = (int)(gid & 3);
    int  bi  = (int)(pix >> 18);           // / (512*512)

    float x = grid[pix * 2 + 0];
    float y = grid[pix * 2 + 1];
    int x0 = (int)floorf(x);
    int y0 = (int)floorf(y);
    int x1 = x0 + 1, y1 = y0 + 1;
    x0 = min(max(x0, 0), Wn - 1);
    x1 = min(max(x1, 0), Wn - 1);
    y0 = min(max(y0, 0), Hn - 1);
    y1 = min(max(y1, 0), Hn - 1);
    // weights from CLIPPED coords (matches reference exactly; edge x==511 -> all-zero weights)
    float x0f = (float)x0, x1f = (float)x1, y0f = (float)y0, y1f = (float)y1;
    float wa = (x1f - x) * (y1f - y);
    float wb = (x1f - x) * (y - y0f);
    float wc = (x - x0f) * (y1f - y);
    float wd = (x - x0f) * (y - y0f);

    long ib = (long)bi * ((long)Hn * Wn * Cn);
    int  co = cg * 4;
    const float4 a4 = *(const float4*)&im[ib + ((long)y0 * Wn + x0) * Cn + co];
    const float4 b4 = *(const float4*)&im[ib + ((long)y1 * Wn + x0) * Cn + co];
    const float4 c4 = *(const float4*)&im[ib + ((long)y0 * Wn + x1) * Cn + co];
    const float4 d4 = *(const float4*)&im[ib + ((long)y1 * Wn + x1) * Cn + co];

    float4 r;
    r.x = wa * a4.x + wb * b4.x + wc * c4.x + wd * d4.x;
    r.y = wa * a4.y + wb * b4.y + wc * c4.y + wd * d4.y;
    r.z = wa * a4.z + wb * b4.z + wc * c4.z + wd * d4.z;
    r.w = wa * a4.w + wb * b4.w + wc * c4.w + wd * d4.w;
    *(float4*)&out[pix * Cn + co] = r;
}

extern "C" void kernel_launch(void* const* d_in, const int* in_sizes, int n_in,
                              void* d_out, int out_size, void* d_ws, size_t ws_size,
                              hipStream_t stream) {
    const float* mov     = (const float*)d_in[0];
    // d_in[1] = ref : unused by the reference computation
    const float* defgrad = (const float*)d_in[2];
    float* out = (float*)d_out;

    const long N_img  = (long)Bn * Hn * Wn * Cn;   // 33554432
    const long N_grid = (long)Bn * Hn * Wn * 2;    // 4194304
    float* mov_def   = out;
    float* ref_def   = out + N_img;
    float* grid_norm = out + 2 * N_img;
    float* grid_inv  = out + 2 * N_img + N_grid;

    grid_x_kernel<<<dim3(Bn * Hn), dim3(512), 0, stream>>>(defgrad, grid_norm, grid_inv);
    grid_y_kernel<<<dim3(Bn * (Wn / 64)), dim3(512), 0, stream>>>(defgrad, grid_norm, grid_inv);

    const long total_threads = (long)Bn * Hn * Wn * 4;   // 4 threads / pixel
    resample_kernel<<<dim3((unsigned)(total_threads / 256)), dim3(256), 0, stream>>>(mov, grid_norm, mov_def);
    resample_kernel<<<dim3((unsigned)(total_threads / 256)), dim3(256), 0, stream>>>(mov_def, grid_inv, ref_def);
}